// Round 4
// baseline (263.059 us; speedup 1.0000x reference)
//
#include <hip/hip_runtime.h>
#include <hip/hip_bf16.h>
#include <stdint.h>

#define EMBED 128
#define HID 145
#define HSTR 160            // per-table padded columns; row = 320 B = 5 x 64 B lines
#define NTILE 20            // 320 output cols / 16
#define KCH 4               // 128 K / 32
#define BINS 8

typedef __attribute__((ext_vector_type(8))) short short8;
typedef __attribute__((ext_vector_type(4))) float f32x4;

__device__ __forceinline__ uint16_t f2bf(float f) {
    uint32_t x = __float_as_uint(f);
    x += 0x7FFFu + ((x >> 16) & 1u);          // round-to-nearest-even
    return (uint16_t)(x >> 16);
}

// ---------------------------------------------------------------------------
// prep_small: detect edge_index dtype; fold cancer-block + b1 into b1p,
// causal columns into wci/wcj; copy W2 zero-padded to 160.
// ---------------------------------------------------------------------------
__global__ void __launch_bounds__(256)
prep_small(const float* __restrict__ cancer, const float* __restrict__ W1,
           const float* __restrict__ b1, const float* __restrict__ W2,
           const void* __restrict__ eiv,
           int* __restrict__ flag, float* __restrict__ b1p, float* __restrict__ wci,
           float* __restrict__ wcj, float* __restrict__ w2p)
{
    const int t = threadIdx.x;
    if (t == 0) {
        // int64 indices < 50000 => every odd 32-bit word is zero.
        const uint32_t* p = (const uint32_t*)eiv;
        uint32_t o = p[1] | p[3] | p[5] | p[7] | p[9] | p[11] | p[13] | p[15];
        *flag = (o == 0u) ? 1 : 0;
    }
    if (t < HSTR) {
        float bv = 0.f, a = 0.f, b = 0.f, w2 = 0.f;
        if (t < HID) {
            float s = b1[t];
            #pragma unroll
            for (int k = 0; k < 32; ++k)
                s = fmaf(cancer[k], W1[(size_t)(2 * EMBED + k) * HID + t], s);
            bv = s;
            a  = W1[(size_t)288 * HID + t] + W1[(size_t)290 * HID + t];  // c_i + diff
            b  = W1[(size_t)289 * HID + t] - W1[(size_t)290 * HID + t];  // c_j - diff
            w2 = W2[t];
        }
        b1p[t] = bv; wci[t] = a; wcj[t] = b; w2p[t] = w2;
    }
}

// ---------------------------------------------------------------------------
// prep_packb: pack W1's A|B halves into bf16 B-fragment order.
// ---------------------------------------------------------------------------
__global__ void __launch_bounds__(256)
prep_packb(const float* __restrict__ W1, short* __restrict__ Wpb)
{
    const int idx = blockIdx.x * 256 + threadIdx.x;   // < 40960
    const int reg  = idx & 7;
    const int lane = (idx >> 3) & 63;
    const int tl   = idx >> 9;                        // 0..79
    const int tt   = tl % NTILE;
    const int kc   = tl / NTILE;
    const int k    = kc * 32 + (lane >> 4) * 8 + reg;
    const int col  = tt * 16 + (lane & 15);
    float val = 0.f;
    if (col < HID)                                 val = W1[(size_t)k * HID + col];
    else if (col >= HSTR && col < HSTR + HID)      val = W1[(size_t)(EMBED + k) * HID + (col - HSTR)];
    Wpb[idx] = (short)f2bf(val);
}

// ---------------------------------------------------------------------------
// bin_hist: per-block (64 blocks) histogram of src-shard bins, ballot-agg.
// ---------------------------------------------------------------------------
__global__ void __launch_bounds__(256)
bin_hist(const void* __restrict__ eiv, const int* __restrict__ flag,
         int E, int nshard, int* __restrict__ counts /* [64][BINS] */)
{
    __shared__ int lh[BINS];
    const int t = threadIdx.x;
    const int lane = t & 63;
    if (t < BINS) lh[t] = 0;
    __syncthreads();
    const int is64 = *flag;
    const long long* e64 = (const long long*)eiv;
    const int*       e32 = (const int*)eiv;
    for (int e = blockIdx.x * 256 + t; e < E; e += 64 * 256) {
        const int src = is64 ? (int)e64[e] : e32[e];
        const int b = src / nshard;
        #pragma unroll
        for (int g = 0; g < BINS; ++g) {
            const unsigned long long m = __ballot(b == g);
            if (m) {
                const int first = __ffsll((unsigned long long)m) - 1;
                if (lane == first) atomicAdd(&lh[g], __popcll(m));
            }
        }
    }
    __syncthreads();
    if (t < BINS) counts[blockIdx.x * BINS + t] = lh[t];
}

// ---------------------------------------------------------------------------
// bin_scan: 1 wave. exclusive scan of counts across 64 blocks per bin;
// totals[g]; zero overflow cursor.
// ---------------------------------------------------------------------------
__global__ void
bin_scan(const int* __restrict__ counts, int* __restrict__ offs,
         int* __restrict__ totals, int* __restrict__ ovfcur)
{
    const int lane = threadIdx.x;      // 64 threads
    if (lane == 0) *ovfcur = 0;
    #pragma unroll
    for (int g = 0; g < BINS; ++g) {
        const int v = counts[lane * BINS + g];
        int s = v;
        #pragma unroll
        for (int d = 1; d < 64; d <<= 1) {
            const int o = __shfl_up(s, d, 64);
            if (lane >= d) s += o;
        }
        offs[lane * BINS + g] = s - v;     // within-bin exclusive prefix
        if (lane == 63) totals[g] = s;     // bin total
    }
}

// ---------------------------------------------------------------------------
// bin_scatter: place each edge's packed record into XCD-interleaved slots.
//   within-bin index c -> slot (c/64)*512 + bin*64 + c%64   (c < CAPB)
//   record = (e << 32) | (src << 16) | dst
// ---------------------------------------------------------------------------
__global__ void __launch_bounds__(256)
bin_scatter(const void* __restrict__ eiv, const int* __restrict__ flag,
            int E, int nshard, int CAPB, const int* __restrict__ offs,
            unsigned long long* __restrict__ perm, int* __restrict__ ovfcur)
{
    __shared__ int cur[BINS];
    const int t = threadIdx.x;
    const int lane = t & 63;
    if (t < BINS) cur[t] = offs[blockIdx.x * BINS + t];
    __syncthreads();
    const int is64 = *flag;
    const long long* e64 = (const long long*)eiv;
    const int*       e32 = (const int*)eiv;
    const int capSlots = BINS * CAPB;

    for (int e = blockIdx.x * 256 + t; e < E; e += 64 * 256) {
        int src, dst;
        if (is64) { src = (int)e64[e]; dst = (int)e64[(size_t)E + e]; }
        else      { src = e32[e];      dst = e32[(size_t)E + e]; }
        const int b = src / nshard;
        int c = 0;
        #pragma unroll
        for (int g = 0; g < BINS; ++g) {
            const unsigned long long m = __ballot(b == g);
            if (b == g) {
                const int first = __ffsll((unsigned long long)m) - 1;
                const int cnt = __popcll(m);
                int base = 0;
                if (lane == first) base = atomicAdd(&cur[g], cnt);
                base = __shfl(base, first, 64);
                c = base + __popcll(m & ((1ull << lane) - 1ull));
            }
        }
        unsigned p;
        if (c < CAPB) p = (unsigned)((c >> 6) * 512 + b * 64 + (c & 63));
        else          p = (unsigned)(capSlots + atomicAdd(ovfcur, 1));
        perm[p] = ((unsigned long long)(unsigned)e << 32)
                | ((unsigned long long)(unsigned)src << 16)
                | (unsigned long long)(unsigned)dst;
    }
}

// ---------------------------------------------------------------------------
// proj_mfma: u'[n] = h[n]@A + b1p + causal[n]*wci   (bf16, HSTR cols)
//            v'[n] = h[n]@B        + causal[n]*wcj
// ---------------------------------------------------------------------------
__global__ void __launch_bounds__(256)
proj_mfma(const float* __restrict__ h, const short* __restrict__ Wpb,
          const float* __restrict__ causal, const float* __restrict__ b1p,
          const float* __restrict__ wci, const float* __restrict__ wcj,
          uint16_t* __restrict__ u, uint16_t* __restrict__ v, int nNodes)
{
    const int t = threadIdx.x;
    const int lane = t & 63;
    const int w = t >> 6;
    const int lane15 = lane & 15, hi = lane >> 4;
    const int nbase = blockIdx.x * 64 + w * 16;

    int nodeA = nbase + lane15;
    if (nodeA >= nNodes) nodeA = nNodes - 1;
    const float* hrow = h + (size_t)nodeA * EMBED + hi * 8;

    short8 afr[KCH];
    #pragma unroll
    for (int kc = 0; kc < KCH; ++kc) {
        const float4 x = *(const float4*)(hrow + kc * 32);
        const float4 y = *(const float4*)(hrow + kc * 32 + 4);
        short8 a;
        a[0] = (short)f2bf(x.x); a[1] = (short)f2bf(x.y);
        a[2] = (short)f2bf(x.z); a[3] = (short)f2bf(x.w);
        a[4] = (short)f2bf(y.x); a[5] = (short)f2bf(y.y);
        a[6] = (short)f2bf(y.z); a[7] = (short)f2bf(y.w);
        afr[kc] = a;
    }

    f32x4 acc[NTILE];
    #pragma unroll
    for (int tt = 0; tt < NTILE; ++tt) acc[tt] = (f32x4){0.f, 0.f, 0.f, 0.f};

    const short8* bp = (const short8*)Wpb;
    #pragma unroll
    for (int kc = 0; kc < KCH; ++kc) {
        #pragma unroll
        for (int tt = 0; tt < NTILE; ++tt) {
            const short8 b = bp[(kc * NTILE + tt) * 64 + lane];
            acc[tt] = __builtin_amdgcn_mfma_f32_16x16x32_bf16(afr[kc], b, acc[tt], 0, 0, 0);
        }
    }

    float cz[4];
    #pragma unroll
    for (int j = 0; j < 4; ++j) {
        const int n = nbase + hi * 4 + j;
        cz[j] = (n < nNodes) ? causal[n] : 0.f;
    }

    #pragma unroll
    for (int tt = 0; tt < NTILE; ++tt) {
        const int col = tt * 16 + lane15;
        const bool isU = (tt < 10);                  // compile-time per tile
        const int ccol = isU ? col : col - HSTR;
        const float addB = isU ? b1p[ccol] : 0.f;
        const float addC = isU ? wci[ccol] : wcj[ccol];
        uint16_t* __restrict__ tab = isU ? u : v;
        #pragma unroll
        for (int j = 0; j < 4; ++j) {
            const int n = nbase + hi * 4 + j;
            if (n < nNodes)
                tab[(size_t)n * HSTR + ccol] = f2bf(acc[tt][j] + fmaf(cz[j], addC, addB));
        }
    }
}

// ---------------------------------------------------------------------------
// edge_binned: block b covers slots [b*64, b*64+64) -> bin b%8 -> XCD b%8.
//   4 lanes per edge, 16 edges per wave; indices come packed in perm.
// ---------------------------------------------------------------------------
__global__ void __launch_bounds__(256)
edge_binned(const unsigned long long* __restrict__ perm,
            const int* __restrict__ totals, const int* __restrict__ ovfcur,
            const uint16_t* __restrict__ u, const uint16_t* __restrict__ v,
            const float* __restrict__ w2p, const float* __restrict__ b2,
            float* __restrict__ out, int CAPB, int totalSlots)
{
    const int t = threadIdx.x;
    const int lane = t & 63;
    const int r = lane & 3;
    const int grp = lane >> 2;
    const int slot = blockIdx.x * 64 + (t >> 6) * 16 + grp;
    const int capSlots = BINS * CAPB;
    const float bias2 = *b2;

    bool ok = slot < totalSlots;
    if (ok) {
        if (slot < capSlots) {
            const int g = (slot >> 6) & 7;
            const int c = (slot >> 9) * 64 + (slot & 63);
            ok = c < totals[g];
        } else {
            ok = (slot - capSlots) < *ovfcur;
        }
    }

    // per-lane W2 slice: chunk cix = 4i+r covers elems 8cix..8cix+7
    const float4* w2f4 = (const float4*)w2p;
    float4 W2a[5], W2b[5];
    #pragma unroll
    for (int i = 0; i < 5; ++i) {
        const int cix = 4 * i + r;
        W2a[i] = w2f4[2 * cix];
        W2b[i] = w2f4[2 * cix + 1];
    }

    const unsigned long long pe = ok ? perm[slot] : 0ull;
    const int e   = (int)(pe >> 32);
    const int src = (int)((pe >> 16) & 0xFFFFull);
    const int dst = (int)(pe & 0xFFFFull);

    const char* ub = (const char*)u + (uint32_t)src * 320u + r * 16;
    const char* vb = (const char*)v + (uint32_t)dst * 320u + r * 16;
    uint4 U[5], V[5];
    #pragma unroll
    for (int i = 0; i < 5; ++i) U[i] = *(const uint4*)(ub + 64 * i);
    #pragma unroll
    for (int i = 0; i < 5; ++i) V[i] = *(const uint4*)(vb + 64 * i);

    float acc0 = 0.f, acc1 = 0.f;
    #pragma unroll
    for (int i = 0; i < 5; ++i) {
        const uint32_t* uw = (const uint32_t*)&U[i];
        const uint32_t* vw = (const uint32_t*)&V[i];
        const float* wA = (const float*)&W2a[i];
        const float* wB = (const float*)&W2b[i];
        #pragma unroll
        for (int p = 0; p < 4; ++p) {
            const float ulo = __uint_as_float(uw[p] << 16);
            const float uhi = __uint_as_float(uw[p] & 0xFFFF0000u);
            const float vlo = __uint_as_float(vw[p] << 16);
            const float vhi = __uint_as_float(vw[p] & 0xFFFF0000u);
            const float t0 = fmaxf(ulo + vlo, 0.f);
            const float t1 = fmaxf(uhi + vhi, 0.f);
            const float wp0 = (p < 2) ? wA[2 * p]     : wB[2 * (p - 2)];
            const float wp1 = (p < 2) ? wA[2 * p + 1] : wB[2 * (p - 2) + 1];
            acc0 = fmaf(t0, wp0, acc0);
            acc1 = fmaf(t1, wp1, acc1);
        }
    }
    float partial = acc0 + acc1;
    partial += __shfl_xor(partial, 1);
    partial += __shfl_xor(partial, 2);
    if (r == 0 && ok)
        out[e] = 1.f / (1.f + __expf(-(partial + bias2)));
}

// ---------------------------------------------------------------------------
// edge_direct: round-3 path (used when ws too small for binning).
// ---------------------------------------------------------------------------
__global__ void __launch_bounds__(256)
edge_direct(const void* __restrict__ eiv,
            const uint16_t* __restrict__ u, const uint16_t* __restrict__ v,
            const float* __restrict__ w2p, const float* __restrict__ b2,
            const int* __restrict__ flag, float* __restrict__ out, int E)
{
    const int t = threadIdx.x;
    const int lane = t & 63;
    const int r = lane & 3;
    const int grp = lane >> 2;
    const int wid = blockIdx.x * (blockDim.x >> 6) + (t >> 6);
    const int eg = wid * 16 + grp;
    const bool ok = eg < E;
    const int e = ok ? eg : 0;
    const int is64 = *flag;
    const float bias2 = *b2;

    const float4* w2f4 = (const float4*)w2p;
    float4 W2a[5], W2b[5];
    #pragma unroll
    for (int i = 0; i < 5; ++i) {
        const int c = 4 * i + r;
        W2a[i] = w2f4[2 * c];
        W2b[i] = w2f4[2 * c + 1];
    }

    int src, dst;
    if (is64) {
        const long long* e64 = (const long long*)eiv;
        src = (int)e64[e]; dst = (int)e64[(size_t)E + e];
    } else {
        const int* e32 = (const int*)eiv;
        src = e32[e];     dst = e32[(size_t)E + e];
    }

    const char* ub = (const char*)u + (uint32_t)src * 320u + r * 16;
    const char* vb = (const char*)v + (uint32_t)dst * 320u + r * 16;
    uint4 U[5], V[5];
    #pragma unroll
    for (int i = 0; i < 5; ++i) U[i] = *(const uint4*)(ub + 64 * i);
    #pragma unroll
    for (int i = 0; i < 5; ++i) V[i] = *(const uint4*)(vb + 64 * i);

    float acc0 = 0.f, acc1 = 0.f;
    #pragma unroll
    for (int i = 0; i < 5; ++i) {
        const uint32_t* uw = (const uint32_t*)&U[i];
        const uint32_t* vw = (const uint32_t*)&V[i];
        const float* wA = (const float*)&W2a[i];
        const float* wB = (const float*)&W2b[i];
        #pragma unroll
        for (int p = 0; p < 4; ++p) {
            const float ulo = __uint_as_float(uw[p] << 16);
            const float uhi = __uint_as_float(uw[p] & 0xFFFF0000u);
            const float vlo = __uint_as_float(vw[p] << 16);
            const float vhi = __uint_as_float(vw[p] & 0xFFFF0000u);
            const float t0 = fmaxf(ulo + vlo, 0.f);
            const float t1 = fmaxf(uhi + vhi, 0.f);
            const float wp0 = (p < 2) ? wA[2 * p]     : wB[2 * (p - 2)];
            const float wp1 = (p < 2) ? wA[2 * p + 1] : wB[2 * (p - 2) + 1];
            acc0 = fmaf(t0, wp0, acc0);
            acc1 = fmaf(t1, wp1, acc1);
        }
    }
    float partial = acc0 + acc1;
    partial += __shfl_xor(partial, 1);
    partial += __shfl_xor(partial, 2);
    if (r == 0 && ok)
        out[e] = 1.f / (1.f + __expf(-(partial + bias2)));
}

// ---------------------------------------------------------------------------
// fallback_kernel: direct per-edge compute (only if workspace too small)
// ---------------------------------------------------------------------------
__global__ void __launch_bounds__(256)
fallback_kernel(const void* __restrict__ eiv, const float* __restrict__ h,
                const float* __restrict__ cancer, const float* __restrict__ causal,
                const float* __restrict__ W1, const float* __restrict__ b1,
                const float* __restrict__ W2, const float* __restrict__ b2,
                float* __restrict__ out, int E)
{
    const int lane = threadIdx.x & 63;
    const int wpb  = blockDim.x >> 6;
    const int wid  = blockIdx.x * wpb + (threadIdx.x >> 6);
    const int nW   = gridDim.x * wpb;
    const uint32_t* p32 = (const uint32_t*)eiv;
    const uint32_t o = p32[1] | p32[3] | p32[5] | p32[7] | p32[9] | p32[11] | p32[13] | p32[15];
    const int is64 = (o == 0u);
    const long long* e64 = (const long long*)eiv;
    const int*       e32 = (const int*)eiv;
    const float bias2 = *b2;

    for (int e = wid; e < E; e += nW) {
        int src, dst;
        if (is64) { src = (int)e64[e]; dst = (int)e64[(size_t)E + e]; }
        else      { src = e32[e];      dst = e32[(size_t)E + e]; }
        const float ci = causal[src], cj = causal[dst];
        float acc0 = 0.f, acc1 = 0.f, acc2 = 0.f;
        const int j0 = lane, j1 = lane + 64, j2 = lane + 128;
        for (int k = 0; k < 291; ++k) {
            float f;
            if      (k < 128) f = h[(size_t)src * 128 + k];
            else if (k < 256) f = h[(size_t)dst * 128 + (k - 128)];
            else if (k < 288) f = cancer[k - 256];
            else if (k == 288) f = ci;
            else if (k == 289) f = cj;
            else               f = ci - cj;
            const float* wr = W1 + (size_t)k * HID;
            acc0 = fmaf(f, wr[j0], acc0);
            acc1 = fmaf(f, wr[j1], acc1);
            if (j2 < HID) acc2 = fmaf(f, wr[j2], acc2);
        }
        float partial = fmaxf(acc0 + b1[j0], 0.f) * W2[j0]
                      + fmaxf(acc1 + b1[j1], 0.f) * W2[j1];
        if (j2 < HID) partial += fmaxf(acc2 + b1[j2], 0.f) * W2[j2];
        #pragma unroll
        for (int m = 32; m; m >>= 1) partial += __shfl_xor(partial, m, 64);
        if (lane == 0) out[e] = 1.f / (1.f + __expf(-(partial + bias2)));
    }
}

// ---------------------------------------------------------------------------
extern "C" void kernel_launch(void* const* d_in, const int* in_sizes, int n_in,
                              void* d_out, int out_size, void* d_ws, size_t ws_size,
                              hipStream_t stream)
{
    const float* h      = (const float*)d_in[0];
    const void*  ei     = d_in[1];
    const float* cancer = (const float*)d_in[2];
    const float* causal = (const float*)d_in[3];
    const float* W1     = (const float*)d_in[4];
    const float* b1     = (const float*)d_in[5];
    const float* W2     = (const float*)d_in[6];
    const float* b2     = (const float*)d_in[7];
    float* outp = (float*)d_out;

    const int nNodes = in_sizes[0] / EMBED;
    const int E      = in_sizes[1] / 2;

    const int nshard = (nNodes + BINS - 1) / BINS;
    const int CAPB   = (((E + BINS - 1) / BINS) * 11 / 10 + 63) & ~63;
    const int capSlots   = BINS * CAPB;
    const int totalSlots = capSlots + ((E + 63) & ~63);

    // workspace layout
    const size_t WPB_OFF  = 8192;                       // 80 KB -> ends 90112
    const size_t CNT_OFF  = 90112;                      // 2 KB
    const size_t OFS_OFF  = 92160;                      // 2 KB
    const size_t TOT_OFF  = 94208;                      // 32 B
    const size_t OVF_OFF  = 94464;                      // 4 B
    const size_t PERM_OFF = 98304;
    const size_t permB    = (size_t)totalSlots * 8;
    const size_t tabB     = (size_t)nNodes * HSTR * sizeof(uint16_t);
    const size_t U_OFFb   = (PERM_OFF + permB + 255) & ~(size_t)255;
    const size_t V_OFFb   = (U_OFFb + tabB + 255) & ~(size_t)255;
    const size_t needBin  = V_OFFb + tabB;
    const size_t U_OFFp   = 98304;
    const size_t V_OFFp   = (U_OFFp + tabB + 255) & ~(size_t)255;
    const size_t needPln  = V_OFFp + tabB;

    char* ws = (char*)d_ws;
    int*   flag = (int*)ws;
    float* b1p  = (float*)(ws + 1024);
    float* wci  = (float*)(ws + 2048);
    float* wcj  = (float*)(ws + 3072);
    float* w2p  = (float*)(ws + 4096);
    short* Wpb  = (short*)(ws + WPB_OFF);

    if (ws_size >= needBin && nNodes <= 65536) {
        int* counts = (int*)(ws + CNT_OFF);
        int* offs   = (int*)(ws + OFS_OFF);
        int* totals = (int*)(ws + TOT_OFF);
        int* ovfc   = (int*)(ws + OVF_OFF);
        unsigned long long* perm = (unsigned long long*)(ws + PERM_OFF);
        uint16_t* u = (uint16_t*)(ws + U_OFFb);
        uint16_t* v = (uint16_t*)(ws + V_OFFb);

        prep_small<<<1, 256, 0, stream>>>(cancer, W1, b1, W2, ei, flag, b1p, wci, wcj, w2p);
        bin_hist<<<64, 256, 0, stream>>>(ei, flag, E, nshard, counts);
        bin_scan<<<1, 64, 0, stream>>>(counts, offs, totals, ovfc);
        bin_scatter<<<64, 256, 0, stream>>>(ei, flag, E, nshard, CAPB, offs, perm, ovfc);
        prep_packb<<<(KCH * NTILE * 64 * 8) / 256, 256, 0, stream>>>(W1, Wpb);
        proj_mfma<<<(nNodes + 63) / 64, 256, 0, stream>>>(h, Wpb, causal, b1p, wci, wcj,
                                                          u, v, nNodes);
        edge_binned<<<(totalSlots + 63) / 64, 256, 0, stream>>>(perm, totals, ovfc, u, v,
                                                                w2p, b2, outp, CAPB,
                                                                totalSlots);
    } else if (ws_size >= needPln) {
        uint16_t* u = (uint16_t*)(ws + U_OFFp);
        uint16_t* v = (uint16_t*)(ws + V_OFFp);

        prep_small<<<1, 256, 0, stream>>>(cancer, W1, b1, W2, ei, flag, b1p, wci, wcj, w2p);
        prep_packb<<<(KCH * NTILE * 64 * 8) / 256, 256, 0, stream>>>(W1, Wpb);
        proj_mfma<<<(nNodes + 63) / 64, 256, 0, stream>>>(h, Wpb, causal, b1p, wci, wcj,
                                                          u, v, nNodes);
        const int waves  = (E + 15) / 16;
        const int blocks = (waves + 3) / 4;
        edge_direct<<<blocks, 256, 0, stream>>>(ei, u, v, w2p, b2, flag, outp, E);
    } else {
        fallback_kernel<<<2048, 256, 0, stream>>>(ei, h, cancer, causal, W1, b1, W2, b2,
                                                  outp, E);
    }
}

// Round 5
// 111.465 us; speedup vs baseline: 2.3600x; 2.3600x over previous
//
#include <hip/hip_runtime.h>
#include <hip/hip_bf16.h>
#include <stdint.h>

#define EMBED 128
#define HID 145
#define HSTR 160            // per-table padded columns; row = 320 B = 5 x 64 B lines
#define NTILE 20            // 320 output cols / 16
#define KCH 4               // 128 K / 32
#define LROW 328            // LDS staging row stride in elems (320 + 8 pad)

typedef __attribute__((ext_vector_type(8))) short short8;
typedef __attribute__((ext_vector_type(4))) float f32x4;

__device__ __forceinline__ uint16_t f2bf(float f) {
    uint32_t x = __float_as_uint(f);
    x += 0x7FFFu + ((x >> 16) & 1u);          // round-to-nearest-even
    return (uint16_t)(x >> 16);
}

// ---------------------------------------------------------------------------
// prep_all: blocks 0..159 pack W1 into bf16 B-fragment order;
//           block 160 folds cancer/b1/causal cols + detects idx dtype.
// ---------------------------------------------------------------------------
__global__ void __launch_bounds__(256)
prep_all(const float* __restrict__ cancer, const float* __restrict__ W1,
         const float* __restrict__ b1, const float* __restrict__ W2,
         const void* __restrict__ eiv,
         int* __restrict__ flag, float* __restrict__ b1p, float* __restrict__ wci,
         float* __restrict__ wcj, float* __restrict__ w2p, short* __restrict__ Wpb)
{
    const int t = threadIdx.x;
    if (blockIdx.x == 160) {
        if (t == 0) {
            // int64 indices < 65536 => every odd 32-bit word is zero.
            const uint32_t* p = (const uint32_t*)eiv;
            uint32_t o = p[1] | p[3] | p[5] | p[7] | p[9] | p[11] | p[13] | p[15];
            *flag = (o == 0u) ? 1 : 0;
        }
        if (t < HSTR) {
            float bv = 0.f, a = 0.f, b = 0.f, w2 = 0.f;
            if (t < HID) {
                float s = b1[t];
                #pragma unroll
                for (int k = 0; k < 32; ++k)
                    s = fmaf(cancer[k], W1[(size_t)(2 * EMBED + k) * HID + t], s);
                bv = s;
                a  = W1[(size_t)288 * HID + t] + W1[(size_t)290 * HID + t];  // c_i + diff
                b  = W1[(size_t)289 * HID + t] - W1[(size_t)290 * HID + t];  // c_j - diff
                w2 = W2[t];
            }
            b1p[t] = bv; wci[t] = a; wcj[t] = b; w2p[t] = w2;
        }
        return;
    }
    const int idx = blockIdx.x * 256 + t;             // < 40960
    const int reg  = idx & 7;
    const int lane = (idx >> 3) & 63;
    const int tl   = idx >> 9;                        // 0..79
    const int tt   = tl % NTILE;
    const int kc   = tl / NTILE;
    const int k    = kc * 32 + (lane >> 4) * 8 + reg;
    const int col  = tt * 16 + (lane & 15);
    float val = 0.f;
    if (col < HID)                             val = W1[(size_t)k * HID + col];
    else if (col >= HSTR && col < HSTR + HID)  val = W1[(size_t)(EMBED + k) * HID + (col - HSTR)];
    Wpb[idx] = (short)f2bf(val);
}

// ---------------------------------------------------------------------------
// pack_pairs: pairs[e] = (src<<16) | dst  (requires nNodes <= 65536)
// ---------------------------------------------------------------------------
__global__ void __launch_bounds__(256)
pack_pairs(const void* __restrict__ eiv, const int* __restrict__ flag,
           uint32_t* __restrict__ pairs, int E)
{
    const int e = blockIdx.x * 256 + threadIdx.x;
    if (e >= E) return;
    const int is64 = *flag;
    uint32_t src, dst;
    if (is64) {
        const long long* e64 = (const long long*)eiv;
        src = (uint32_t)e64[e]; dst = (uint32_t)e64[(size_t)E + e];
    } else {
        const uint32_t* e32 = (const uint32_t*)eiv;
        src = e32[e];           dst = e32[(size_t)E + e];
    }
    pairs[e] = (src << 16) | (dst & 0xFFFFu);
}

// ---------------------------------------------------------------------------
// proj_mfma: u'[n] = h[n]@A + b1p + causal[n]*wci   (bf16, HSTR cols)
//            v'[n] = h[n]@B        + causal[n]*wcj
//   block = 4 waves = 64 nodes; wave computes 16 nodes x 320 cols via
//   20 tiles of mfma_f32_16x16x32_bf16 over 4 K-chunks.
//   Epilogue stages bf16 results in LDS (immediate-offset ds_write_b16),
//   then the whole block copies out with coalesced dwordx4 stores
//   (global byte offset = 16*f, contiguous across threads).
// ---------------------------------------------------------------------------
__global__ void __launch_bounds__(256)
proj_mfma(const float* __restrict__ h, const short* __restrict__ Wpb,
          const float* __restrict__ causal, const float* __restrict__ b1p,
          const float* __restrict__ wci, const float* __restrict__ wcj,
          uint16_t* __restrict__ u, uint16_t* __restrict__ v, int nNodes)
{
    __shared__ uint16_t lds[64 * LROW];
    const int t = threadIdx.x;
    const int lane = t & 63;
    const int w = t >> 6;
    const int lane15 = lane & 15, hi = lane >> 4;
    const int n0blk = blockIdx.x * 64;
    const int nbase = n0blk + w * 16;

    int nodeA = nbase + lane15;
    if (nodeA >= nNodes) nodeA = nNodes - 1;
    const float* hrow = h + (size_t)nodeA * EMBED + hi * 8;

    short8 afr[KCH];
    #pragma unroll
    for (int kc = 0; kc < KCH; ++kc) {
        const float4 x = *(const float4*)(hrow + kc * 32);
        const float4 y = *(const float4*)(hrow + kc * 32 + 4);
        short8 a;
        a[0] = (short)f2bf(x.x); a[1] = (short)f2bf(x.y);
        a[2] = (short)f2bf(x.z); a[3] = (short)f2bf(x.w);
        a[4] = (short)f2bf(y.x); a[5] = (short)f2bf(y.y);
        a[6] = (short)f2bf(y.z); a[7] = (short)f2bf(y.w);
        afr[kc] = a;
    }

    f32x4 acc[NTILE];
    #pragma unroll
    for (int tt = 0; tt < NTILE; ++tt) acc[tt] = (f32x4){0.f, 0.f, 0.f, 0.f};

    const short8* bp = (const short8*)Wpb;
    #pragma unroll
    for (int kc = 0; kc < KCH; ++kc) {
        #pragma unroll
        for (int tt = 0; tt < NTILE; ++tt) {
            const short8 b = bp[(kc * NTILE + tt) * 64 + lane];
            acc[tt] = __builtin_amdgcn_mfma_f32_16x16x32_bf16(afr[kc], b, acc[tt], 0, 0, 0);
        }
    }

    float cz[4];
    #pragma unroll
    for (int j = 0; j < 4; ++j) {
        const int n = nbase + hi * 4 + j;
        cz[j] = (n < nNodes) ? causal[n] : 0.f;
    }

    // epilogue -> LDS staging (single base reg + immediate offsets)
    uint16_t* lbase = lds + (w * 16 + hi * 4) * LROW + lane15;
    #pragma unroll
    for (int tt = 0; tt < NTILE; ++tt) {
        const int col = tt * 16 + lane15;
        const bool isU = (tt < 10);                  // compile-time per tile
        const int ccol = isU ? col : col - HSTR;
        const float addB = isU ? b1p[ccol] : 0.f;
        const float addC = isU ? wci[ccol] : wcj[ccol];
        #pragma unroll
        for (int j = 0; j < 4; ++j)
            lbase[j * LROW + tt * 16] = f2bf(acc[tt][j] + fmaf(cz[j], addC, addB));
    }
    __syncthreads();

    // block-wide coalesced copy-out: f in [0,1280), n=f/20, chunk c8=f%20
    // global offset = 16*f bytes into u/v at node base n0blk (rows contiguous)
    char* ug = (char*)u + (size_t)n0blk * 320;
    char* vg = (char*)v + (size_t)n0blk * 320;
    if (n0blk + 64 <= nNodes) {
        #pragma unroll
        for (int i = 0; i < 5; ++i) {
            const int f = i * 256 + t;
            const int n = f / 20, c8 = f % 20;
            const uint16_t* ls = lds + n * LROW + c8 * 8;
            *(uint4*)(ug + 16 * f) = *(const uint4*)ls;
            *(uint4*)(vg + 16 * f) = *(const uint4*)(ls + HSTR);
        }
    } else {
        #pragma unroll
        for (int i = 0; i < 5; ++i) {
            const int f = i * 256 + t;
            const int n = f / 20, c8 = f % 20;
            if (n0blk + n < nNodes) {
                const uint16_t* ls = lds + n * LROW + c8 * 8;
                *(uint4*)(ug + 16 * f) = *(const uint4*)ls;
                *(uint4*)(vg + 16 * f) = *(const uint4*)(ls + HSTR);
            }
        }
    }
}

// ---------------------------------------------------------------------------
// edge_pairs: 4 lanes per edge, 16 edges per wave; single u32 idx load/edge.
// ---------------------------------------------------------------------------
__global__ void __launch_bounds__(256)
edge_pairs(const uint32_t* __restrict__ pairs,
           const uint16_t* __restrict__ u, const uint16_t* __restrict__ v,
           const float* __restrict__ w2p, const float* __restrict__ b2,
           float* __restrict__ out, int E)
{
    const int t = threadIdx.x;
    const int lane = t & 63;
    const int r = lane & 3;                 // chunk lane within 4-lane group
    const int grp = lane >> 2;              // 0..15: edge group within wave
    const int wid = blockIdx.x * (blockDim.x >> 6) + (t >> 6);
    const int eg = wid * 16 + grp;
    const bool ok = eg < E;
    const int e = ok ? eg : 0;
    const float bias2 = *b2;

    // per-lane W2 slice: chunk c = 4i+r covers elems 8c..8c+7
    const float4* w2f4 = (const float4*)w2p;
    float4 W2a[5], W2b[5];
    #pragma unroll
    for (int i = 0; i < 5; ++i) {
        const int c = 4 * i + r;
        W2a[i] = w2f4[2 * c];
        W2b[i] = w2f4[2 * c + 1];
    }

    const uint32_t pr = pairs[e];
    const uint32_t src = pr >> 16;
    const uint32_t dst = pr & 0xFFFFu;

    const char* ub = (const char*)u + src * 320u + r * 16;
    const char* vb = (const char*)v + dst * 320u + r * 16;
    uint4 U[5], V[5];
    #pragma unroll
    for (int i = 0; i < 5; ++i) U[i] = *(const uint4*)(ub + 64 * i);
    #pragma unroll
    for (int i = 0; i < 5; ++i) V[i] = *(const uint4*)(vb + 64 * i);

    float acc0 = 0.f, acc1 = 0.f;
    #pragma unroll
    for (int i = 0; i < 5; ++i) {
        const uint32_t* uw = (const uint32_t*)&U[i];
        const uint32_t* vw = (const uint32_t*)&V[i];
        const float* wA = (const float*)&W2a[i];
        const float* wB = (const float*)&W2b[i];
        #pragma unroll
        for (int p = 0; p < 4; ++p) {
            const float ulo = __uint_as_float(uw[p] << 16);
            const float uhi = __uint_as_float(uw[p] & 0xFFFF0000u);
            const float vlo = __uint_as_float(vw[p] << 16);
            const float vhi = __uint_as_float(vw[p] & 0xFFFF0000u);
            const float t0 = fmaxf(ulo + vlo, 0.f);
            const float t1 = fmaxf(uhi + vhi, 0.f);
            const float wp0 = (p < 2) ? wA[2 * p]     : wB[2 * (p - 2)];
            const float wp1 = (p < 2) ? wA[2 * p + 1] : wB[2 * (p - 2) + 1];
            acc0 = fmaf(t0, wp0, acc0);
            acc1 = fmaf(t1, wp1, acc1);
        }
    }
    float partial = acc0 + acc1;
    partial += __shfl_xor(partial, 1);
    partial += __shfl_xor(partial, 2);
    if (r == 0 && ok)
        out[e] = 1.f / (1.f + __expf(-(partial + bias2)));
}

// ---------------------------------------------------------------------------
// edge_direct: round-3 path (used when nNodes > 65536; reads raw edge_index).
// ---------------------------------------------------------------------------
__global__ void __launch_bounds__(256)
edge_direct(const void* __restrict__ eiv,
            const uint16_t* __restrict__ u, const uint16_t* __restrict__ v,
            const float* __restrict__ w2p, const float* __restrict__ b2,
            const int* __restrict__ flag, float* __restrict__ out, int E)
{
    const int t = threadIdx.x;
    const int lane = t & 63;
    const int r = lane & 3;
    const int grp = lane >> 2;
    const int wid = blockIdx.x * (blockDim.x >> 6) + (t >> 6);
    const int eg = wid * 16 + grp;
    const bool ok = eg < E;
    const int e = ok ? eg : 0;
    const int is64 = *flag;
    const float bias2 = *b2;

    const float4* w2f4 = (const float4*)w2p;
    float4 W2a[5], W2b[5];
    #pragma unroll
    for (int i = 0; i < 5; ++i) {
        const int c = 4 * i + r;
        W2a[i] = w2f4[2 * c];
        W2b[i] = w2f4[2 * c + 1];
    }

    size_t src, dst;
    if (is64) {
        const long long* e64 = (const long long*)eiv;
        src = (size_t)e64[e]; dst = (size_t)e64[(size_t)E + e];
    } else {
        const int* e32 = (const int*)eiv;
        src = (size_t)e32[e]; dst = (size_t)e32[(size_t)E + e];
    }

    const char* ub = (const char*)u + src * 320u + r * 16;
    const char* vb = (const char*)v + dst * 320u + r * 16;
    uint4 U[5], V[5];
    #pragma unroll
    for (int i = 0; i < 5; ++i) U[i] = *(const uint4*)(ub + 64 * i);
    #pragma unroll
    for (int i = 0; i < 5; ++i) V[i] = *(const uint4*)(vb + 64 * i);

    float acc0 = 0.f, acc1 = 0.f;
    #pragma unroll
    for (int i = 0; i < 5; ++i) {
        const uint32_t* uw = (const uint32_t*)&U[i];
        const uint32_t* vw = (const uint32_t*)&V[i];
        const float* wA = (const float*)&W2a[i];
        const float* wB = (const float*)&W2b[i];
        #pragma unroll
        for (int p = 0; p < 4; ++p) {
            const float ulo = __uint_as_float(uw[p] << 16);
            const float uhi = __uint_as_float(uw[p] & 0xFFFF0000u);
            const float vlo = __uint_as_float(vw[p] << 16);
            const float vhi = __uint_as_float(vw[p] & 0xFFFF0000u);
            const float t0 = fmaxf(ulo + vlo, 0.f);
            const float t1 = fmaxf(uhi + vhi, 0.f);
            const float wp0 = (p < 2) ? wA[2 * p]     : wB[2 * (p - 2)];
            const float wp1 = (p < 2) ? wA[2 * p + 1] : wB[2 * (p - 2) + 1];
            acc0 = fmaf(t0, wp0, acc0);
            acc1 = fmaf(t1, wp1, acc1);
        }
    }
    float partial = acc0 + acc1;
    partial += __shfl_xor(partial, 1);
    partial += __shfl_xor(partial, 2);
    if (r == 0 && ok)
        out[e] = 1.f / (1.f + __expf(-(partial + bias2)));
}

// ---------------------------------------------------------------------------
// fallback_kernel: direct per-edge compute (only if workspace too small)
// ---------------------------------------------------------------------------
__global__ void __launch_bounds__(256)
fallback_kernel(const void* __restrict__ eiv, const float* __restrict__ h,
                const float* __restrict__ cancer, const float* __restrict__ causal,
                const float* __restrict__ W1, const float* __restrict__ b1,
                const float* __restrict__ W2, const float* __restrict__ b2,
                float* __restrict__ out, int E)
{
    const int lane = threadIdx.x & 63;
    const int wpb  = blockDim.x >> 6;
    const int wid  = blockIdx.x * wpb + (threadIdx.x >> 6);
    const int nW   = gridDim.x * wpb;
    const uint32_t* p32 = (const uint32_t*)eiv;
    const uint32_t o = p32[1] | p32[3] | p32[5] | p32[7] | p32[9] | p32[11] | p32[13] | p32[15];
    const int is64 = (o == 0u);
    const long long* e64 = (const long long*)eiv;
    const int*       e32 = (const int*)eiv;
    const float bias2 = *b2;

    for (int e = wid; e < E; e += nW) {
        long long src, dst;
        if (is64) { src = e64[e]; dst = e64[(size_t)E + e]; }
        else      { src = e32[e]; dst = e32[(size_t)E + e]; }
        const float ci = causal[src], cj = causal[dst];
        float acc0 = 0.f, acc1 = 0.f, acc2 = 0.f;
        const int j0 = lane, j1 = lane + 64, j2 = lane + 128;
        for (int k = 0; k < 291; ++k) {
            float f;
            if      (k < 128) f = h[(size_t)src * 128 + k];
            else if (k < 256) f = h[(size_t)dst * 128 + (k - 128)];
            else if (k < 288) f = cancer[k - 256];
            else if (k == 288) f = ci;
            else if (k == 289) f = cj;
            else               f = ci - cj;
            const float* wr = W1 + (size_t)k * HID;
            acc0 = fmaf(f, wr[j0], acc0);
            acc1 = fmaf(f, wr[j1], acc1);
            if (j2 < HID) acc2 = fmaf(f, wr[j2], acc2);
        }
        float partial = fmaxf(acc0 + b1[j0], 0.f) * W2[j0]
                      + fmaxf(acc1 + b1[j1], 0.f) * W2[j1];
        if (j2 < HID) partial += fmaxf(acc2 + b1[j2], 0.f) * W2[j2];
        #pragma unroll
        for (int m = 32; m; m >>= 1) partial += __shfl_xor(partial, m, 64);
        if (lane == 0) out[e] = 1.f / (1.f + __expf(-(partial + bias2)));
    }
}

// ---------------------------------------------------------------------------
extern "C" void kernel_launch(void* const* d_in, const int* in_sizes, int n_in,
                              void* d_out, int out_size, void* d_ws, size_t ws_size,
                              hipStream_t stream)
{
    const float* h      = (const float*)d_in[0];
    const void*  ei     = d_in[1];
    const float* cancer = (const float*)d_in[2];
    const float* causal = (const float*)d_in[3];
    const float* W1     = (const float*)d_in[4];
    const float* b1     = (const float*)d_in[5];
    const float* W2     = (const float*)d_in[6];
    const float* b2     = (const float*)d_in[7];
    float* outp = (float*)d_out;

    const int nNodes = in_sizes[0] / EMBED;
    const int E      = in_sizes[1] / 2;

    // workspace layout
    const size_t WPB_OFF   = 8192;                      // 80 KB -> ends 90112
    const size_t PAIRS_OFF = 98304;
    const size_t pairsB    = ((size_t)E * 4 + 255) & ~(size_t)255;
    const size_t tabB      = (size_t)nNodes * HSTR * sizeof(uint16_t);
    const size_t U_OFF     = PAIRS_OFF + pairsB;
    const size_t V_OFF     = (U_OFF + tabB + 255) & ~(size_t)255;
    const size_t need      = V_OFF + tabB;

    char* ws = (char*)d_ws;
    int*   flag = (int*)ws;
    float* b1p  = (float*)(ws + 1024);
    float* wci  = (float*)(ws + 2048);
    float* wcj  = (float*)(ws + 3072);
    float* w2p  = (float*)(ws + 4096);
    short* Wpb  = (short*)(ws + WPB_OFF);

    if (ws_size >= need) {
        uint32_t* pairs = (uint32_t*)(ws + PAIRS_OFF);
        uint16_t* u     = (uint16_t*)(ws + U_OFF);
        uint16_t* v     = (uint16_t*)(ws + V_OFF);

        prep_all<<<161, 256, 0, stream>>>(cancer, W1, b1, W2, ei, flag,
                                          b1p, wci, wcj, w2p, Wpb);
        const int waves  = (E + 15) / 16;
        const int blocks = (waves + 3) / 4;
        if (nNodes <= 65536) {
            pack_pairs<<<(E + 255) / 256, 256, 0, stream>>>(ei, flag, pairs, E);
            proj_mfma<<<(nNodes + 63) / 64, 256, 0, stream>>>(h, Wpb, causal, b1p,
                                                              wci, wcj, u, v, nNodes);
            edge_pairs<<<blocks, 256, 0, stream>>>(pairs, u, v, w2p, b2, outp, E);
        } else {
            proj_mfma<<<(nNodes + 63) / 64, 256, 0, stream>>>(h, Wpb, causal, b1p,
                                                              wci, wcj, u, v, nNodes);
            edge_direct<<<blocks, 256, 0, stream>>>(ei, u, v, w2p, b2, flag, outp, E);
        }
    } else {
        fallback_kernel<<<2048, 256, 0, stream>>>(ei, h, cancer, causal, W1, b1, W2, b2,
                                                  outp, E);
    }
}

// Round 6
// 97.188 us; speedup vs baseline: 2.7067x; 1.1469x over previous
//
#include <hip/hip_runtime.h>
#include <hip/hip_bf16.h>
#include <stdint.h>

#define EMBED 128
#define HID 145
#define HSTR 160            // padded col count per table
#define NTILE 20            // 320 output cols / 16
#define KCH 4               // 128 K / 32
#define ROWB 192            // int8 row: [0:160) permuted bytes, [160:164) f32 scale, pad
#define LDSROW 208          // LDS staging row stride (bank-spread)

typedef __attribute__((ext_vector_type(8))) short short8;
typedef __attribute__((ext_vector_type(4))) float f32x4;

__device__ __forceinline__ uint16_t f2bf(float f) {
    uint32_t x = __float_as_uint(f);
    x += 0x7FFFu + ((x >> 16) & 1u);          // round-to-nearest-even
    return (uint16_t)(x >> 16);
}

// ---------------------------------------------------------------------------
// prep_fused: blocks [0,P): pack pairs[e]=(src<<16)|dst
//             blocks [P,P+160): pack W1 into bf16 B-fragment order (Wpb)
//             block P+160: fold cancer/b1/causal cols; permuted w2p (192 f)
// ---------------------------------------------------------------------------
__global__ void __launch_bounds__(256)
prep_fused(const float* __restrict__ cancer, const float* __restrict__ W1,
           const float* __restrict__ b1, const float* __restrict__ W2,
           const void* __restrict__ eiv, int E, int P,
           float* __restrict__ b1p, float* __restrict__ wci,
           float* __restrict__ wcj, float* __restrict__ w2p,
           short* __restrict__ Wpb, uint32_t* __restrict__ pairs)
{
    const int t = threadIdx.x;
    const int b = blockIdx.x;
    if (b < P) {
        // int64 indices < 65536 => every odd 32-bit word is zero.
        const uint32_t* pw = (const uint32_t*)eiv;
        const uint32_t odd = pw[1] | pw[3] | pw[5] | pw[7] | pw[9] | pw[11] | pw[13] | pw[15];
        const int is64 = (odd == 0u);
        const int e = b * 256 + t;
        if (e < E) {
            uint32_t src, dst;
            if (is64) {
                const long long* e64 = (const long long*)eiv;
                src = (uint32_t)e64[e]; dst = (uint32_t)e64[(size_t)E + e];
            } else {
                const uint32_t* e32 = (const uint32_t*)eiv;
                src = e32[e];           dst = e32[(size_t)E + e];
            }
            pairs[e] = (src << 16) | (dst & 0xFFFFu);
        }
        return;
    }
    if (b < P + 160) {
        const int idx = (b - P) * 256 + t;            // < 40960
        const int reg  = idx & 7;
        const int lane = (idx >> 3) & 63;
        const int tl   = idx >> 9;                    // 0..79
        const int tt   = tl % NTILE;
        const int kc   = tl / NTILE;
        const int k    = kc * 32 + (lane >> 4) * 8 + reg;
        const int col  = tt * 16 + (lane & 15);
        float val = 0.f;
        if (col < HID)                             val = W1[(size_t)k * HID + col];
        else if (col >= HSTR && col < HSTR + HID)  val = W1[(size_t)(EMBED + k) * HID + (col - HSTR)];
        Wpb[idx] = (short)f2bf(val);
        return;
    }
    // smalls
    if (t < HSTR) {
        float bv = 0.f, a = 0.f, bb = 0.f;
        if (t < HID) {
            float s = b1[t];
            #pragma unroll
            for (int k = 0; k < 32; ++k)
                s = fmaf(cancer[k], W1[(size_t)(2 * EMBED + k) * HID + t], s);
            bv = s;
            a  = W1[(size_t)288 * HID + t] + W1[(size_t)290 * HID + t];  // c_i + diff
            bb = W1[(size_t)289 * HID + t] - W1[(size_t)290 * HID + t];  // c_j - diff
        }
        b1p[t] = bv; wci[t] = a; wcj[t] = bb;
    }
    if (t < ROWB) {
        // permuted W2 by byte position: pos p -> col (p%10)*16 + p/10
        float w2 = 0.f;
        if (t < HSTR) {
            const int col = (t % 10) * 16 + (t / 10);
            if (col < HID) w2 = W2[col];
        }
        w2p[t] = w2;
    }
}

// ---------------------------------------------------------------------------
// proj_mfma: u'[n] = h[n]@A + b1p + causal[n]*wci   (int8 rowscale, ROWB row)
//            v'[n] = h[n]@B        + causal[n]*wcj
//   block = 4 waves = 64 nodes; wave computes 16 nodes x 320 cols via
//   20 tiles of mfma_f32_16x16x32_bf16 over 4 K-chunks.
//   Epilogue: fold -> per-row absmax (4x shfl_xor over lane15) -> int8
//   quantize (biased +128) -> LDS staging (5x ds_write_b16/lane/row) ->
//   block-wide coalesced dwordx4 copy-out. Byte pos(col)=(col&15)*10+(col>>4).
// ---------------------------------------------------------------------------
__global__ void __launch_bounds__(256)
proj_mfma(const float* __restrict__ h, const short* __restrict__ Wpb,
          const float* __restrict__ causal, const float* __restrict__ b1p,
          const float* __restrict__ wci, const float* __restrict__ wcj,
          uint8_t* __restrict__ u, uint8_t* __restrict__ v, int nNodes)
{
    __shared__ uint8_t lds[2 * 64 * LDSROW];
    const int t = threadIdx.x;
    const int lane = t & 63;
    const int w = t >> 6;
    const int lane15 = lane & 15, hi = lane >> 4;
    const int n0blk = blockIdx.x * 64;
    const int nbase = n0blk + w * 16;

    int nodeA = nbase + lane15;
    if (nodeA >= nNodes) nodeA = nNodes - 1;
    const float* hrow = h + (size_t)nodeA * EMBED + hi * 8;

    short8 afr[KCH];
    #pragma unroll
    for (int kc = 0; kc < KCH; ++kc) {
        const float4 x = *(const float4*)(hrow + kc * 32);
        const float4 y = *(const float4*)(hrow + kc * 32 + 4);
        short8 a;
        a[0] = (short)f2bf(x.x); a[1] = (short)f2bf(x.y);
        a[2] = (short)f2bf(x.z); a[3] = (short)f2bf(x.w);
        a[4] = (short)f2bf(y.x); a[5] = (short)f2bf(y.y);
        a[6] = (short)f2bf(y.z); a[7] = (short)f2bf(y.w);
        afr[kc] = a;
    }

    f32x4 acc[NTILE];
    #pragma unroll
    for (int tt = 0; tt < NTILE; ++tt) acc[tt] = (f32x4){0.f, 0.f, 0.f, 0.f};

    const short8* bp = (const short8*)Wpb;
    #pragma unroll
    for (int kc = 0; kc < KCH; ++kc) {
        #pragma unroll
        for (int tt = 0; tt < NTILE; ++tt) {
            const short8 b = bp[(kc * NTILE + tt) * 64 + lane];
            acc[tt] = __builtin_amdgcn_mfma_f32_16x16x32_bf16(afr[kc], b, acc[tt], 0, 0, 0);
        }
    }

    float cz[4];
    #pragma unroll
    for (int j = 0; j < 4; ++j) {
        const int n = nbase + hi * 4 + j;
        cz[j] = (n < nNodes) ? causal[n] : 0.f;
    }

    // fold bias/causal terms in place
    #pragma unroll
    for (int tt = 0; tt < NTILE; ++tt) {
        const int col = tt * 16 + lane15;
        const bool isU = (tt < 10);
        const int ccol = isU ? col : col - HSTR;
        const float addB = isU ? b1p[ccol] : 0.f;
        const float addC = isU ? wci[ccol] : wcj[ccol];
        #pragma unroll
        for (int j = 0; j < 4; ++j)
            acc[tt][j] = acc[tt][j] + fmaf(cz[j], addC, addB);
    }

    uint8_t* ldsu = lds;
    uint8_t* ldsv = lds + 64 * LDSROW;

    #pragma unroll
    for (int j = 0; j < 4; ++j) {
        float mu = 0.f, mv = 0.f;
        #pragma unroll
        for (int tt = 0; tt < 10; ++tt)  mu = fmaxf(mu, fabsf(acc[tt][j]));
        #pragma unroll
        for (int tt = 10; tt < 20; ++tt) mv = fmaxf(mv, fabsf(acc[tt][j]));
        #pragma unroll
        for (int m = 1; m < 16; m <<= 1) {
            mu = fmaxf(mu, __shfl_xor(mu, m));
            mv = fmaxf(mv, __shfl_xor(mv, m));
        }
        mu = fmaxf(mu, 1e-20f); mv = fmaxf(mv, 1e-20f);
        const float invu = 127.f / mu, su = mu * (1.f / 127.f);
        const float invv = 127.f / mv, sv = mv * (1.f / 127.f);
        const int row = w * 16 + hi * 4 + j;
        if (lane15 == 0) {
            *(float*)(ldsu + row * LDSROW + HSTR) = su;
            *(float*)(ldsv + row * LDSROW + HSTR) = sv;
        }
        uint8_t* lu = ldsu + row * LDSROW + lane15 * 10;
        uint8_t* lv = ldsv + row * LDSROW + lane15 * 10;
        #pragma unroll
        for (int k = 0; k < 5; ++k) {
            const uint32_t q0 = (uint32_t)(acc[2 * k][j]     * invu + 128.5f);
            const uint32_t q1 = (uint32_t)(acc[2 * k + 1][j] * invu + 128.5f);
            *(uint16_t*)(lu + 2 * k) = (uint16_t)(q0 | (q1 << 8));
            const uint32_t p0 = (uint32_t)(acc[10 + 2 * k][j]     * invv + 128.5f);
            const uint32_t p1 = (uint32_t)(acc[10 + 2 * k + 1][j] * invv + 128.5f);
            *(uint16_t*)(lv + 2 * k) = (uint16_t)(p0 | (p1 << 8));
        }
    }
    __syncthreads();

    // block-wide coalesced copy-out: f in [0,768), row=f/12, off=(f%12)*16
    char* ug = (char*)u + (size_t)n0blk * ROWB;
    char* vg = (char*)v + (size_t)n0blk * ROWB;
    if (n0blk + 64 <= nNodes) {
        #pragma unroll
        for (int i = 0; i < 3; ++i) {
            const int f = i * 256 + t;
            const int row = f / 12, off = (f % 12) * 16;
            *(uint4*)(ug + 16 * f) = *(const uint4*)(ldsu + row * LDSROW + off);
            *(uint4*)(vg + 16 * f) = *(const uint4*)(ldsv + row * LDSROW + off);
        }
    } else {
        #pragma unroll
        for (int i = 0; i < 3; ++i) {
            const int f = i * 256 + t;
            const int row = f / 12, off = (f % 12) * 16;
            if (n0blk + row < nNodes) {
                *(uint4*)(ug + 16 * f) = *(const uint4*)(ldsu + row * LDSROW + off);
                *(uint4*)(vg + 16 * f) = *(const uint4*)(ldsv + row * LDSROW + off);
            }
        }
    }
}

// ---------------------------------------------------------------------------
// edge_int8: 4 lanes per edge, 16 edges per wave. Lane r reads bytes
//   [r*48, r*48+48) of u'[src] and v'[dst] rows (3 uint4 each, 3 lines/row).
//   Scale rides in lane 3's second load word; broadcast via shfl.
//   Pad/scale bytes decode to finite floats x w2=0 -> no masking needed.
// ---------------------------------------------------------------------------
__global__ void __launch_bounds__(256)
edge_int8(const uint32_t* __restrict__ pairs,
          const uint8_t* __restrict__ u, const uint8_t* __restrict__ v,
          const float* __restrict__ w2p, const float* __restrict__ b2,
          float* __restrict__ out, int E)
{
    const int t = threadIdx.x;
    const int lane = t & 63;
    const int r = lane & 3;                 // byte-chunk lane within group
    const int grp = lane >> 2;              // 0..15: edge within wave
    const int wid = blockIdx.x * (blockDim.x >> 6) + (t >> 6);
    const int eg = wid * 16 + grp;
    const bool ok = eg < E;
    const int e = ok ? eg : 0;
    const float bias2 = *b2;

    // per-lane permuted W2 slice: 48 floats
    const float4* wq = (const float4*)w2p + r * 12;
    float4 W2r[12];
    #pragma unroll
    for (int i = 0; i < 12; ++i) W2r[i] = wq[i];

    const uint32_t pr = pairs[e];
    const uint32_t src = pr >> 16;
    const uint32_t dst = pr & 0xFFFFu;

    const char* ub = (const char*)u + src * (uint32_t)ROWB + r * 48;
    const char* vb = (const char*)v + dst * (uint32_t)ROWB + r * 48;
    uint4 U[3], V[3];
    #pragma unroll
    for (int i = 0; i < 3; ++i) U[i] = *(const uint4*)(ub + 16 * i);
    #pragma unroll
    for (int i = 0; i < 3; ++i) V[i] = *(const uint4*)(vb + 16 * i);

    // scales live at row bytes 160..163 = lane r=3, word U[1].x
    const float su = __shfl(__uint_as_float(U[1].x), lane | 3);
    const float sv = __shfl(__uint_as_float(V[1].x), lane | 3);
    const float off = -128.f * (su + sv);

    float acc = 0.f;
    const float* w2f = (const float*)W2r;
    #pragma unroll
    for (int i = 0; i < 3; ++i) {
        const uint32_t* uw = (const uint32_t*)&U[i];
        const uint32_t* vw = (const uint32_t*)&V[i];
        #pragma unroll
        for (int d = 0; d < 4; ++d) {
            const uint32_t uword = uw[d], vword = vw[d];
            #pragma unroll
            for (int k = 0; k < 4; ++k) {
                const float uf = (float)((uword >> (8 * k)) & 0xFFu);
                const float vf = (float)((vword >> (8 * k)) & 0xFFu);
                float tv = fmaf(su, uf, fmaf(sv, vf, off));
                tv = fmaxf(tv, 0.f);
                acc = fmaf(tv, w2f[i * 16 + d * 4 + k], acc);
            }
        }
    }
    float partial = acc;
    partial += __shfl_xor(partial, 1);
    partial += __shfl_xor(partial, 2);
    if (r == 0 && ok)
        out[e] = 1.f / (1.f + __expf(-(partial + bias2)));
}

// ---------------------------------------------------------------------------
// fallback_kernel: direct per-edge compute (ws too small or nNodes > 65536)
// ---------------------------------------------------------------------------
__global__ void __launch_bounds__(256)
fallback_kernel(const void* __restrict__ eiv, const float* __restrict__ h,
                const float* __restrict__ cancer, const float* __restrict__ causal,
                const float* __restrict__ W1, const float* __restrict__ b1,
                const float* __restrict__ W2, const float* __restrict__ b2,
                float* __restrict__ out, int E)
{
    const int lane = threadIdx.x & 63;
    const int wpb  = blockDim.x >> 6;
    const int wid  = blockIdx.x * wpb + (threadIdx.x >> 6);
    const int nW   = gridDim.x * wpb;
    const uint32_t* p32 = (const uint32_t*)eiv;
    const uint32_t o = p32[1] | p32[3] | p32[5] | p32[7] | p32[9] | p32[11] | p32[13] | p32[15];
    const int is64 = (o == 0u);
    const long long* e64 = (const long long*)eiv;
    const int*       e32 = (const int*)eiv;
    const float bias2 = *b2;

    for (int e = wid; e < E; e += nW) {
        long long src, dst;
        if (is64) { src = e64[e]; dst = e64[(size_t)E + e]; }
        else      { src = e32[e]; dst = e32[(size_t)E + e]; }
        const float ci = causal[src], cj = causal[dst];
        float acc0 = 0.f, acc1 = 0.f, acc2 = 0.f;
        const int j0 = lane, j1 = lane + 64, j2 = lane + 128;
        for (int k = 0; k < 291; ++k) {
            float f;
            if      (k < 128) f = h[(size_t)src * 128 + k];
            else if (k < 256) f = h[(size_t)dst * 128 + (k - 128)];
            else if (k < 288) f = cancer[k - 256];
            else if (k == 288) f = ci;
            else if (k == 289) f = cj;
            else               f = ci - cj;
            const float* wr = W1 + (size_t)k * HID;
            acc0 = fmaf(f, wr[j0], acc0);
            acc1 = fmaf(f, wr[j1], acc1);
            if (j2 < HID) acc2 = fmaf(f, wr[j2], acc2);
        }
        float partial = fmaxf(acc0 + b1[j0], 0.f) * W2[j0]
                      + fmaxf(acc1 + b1[j1], 0.f) * W2[j1];
        if (j2 < HID) partial += fmaxf(acc2 + b1[j2], 0.f) * W2[j2];
        #pragma unroll
        for (int m = 32; m; m >>= 1) partial += __shfl_xor(partial, m, 64);
        if (lane == 0) out[e] = 1.f / (1.f + __expf(-(partial + bias2)));
    }
}

// ---------------------------------------------------------------------------
extern "C" void kernel_launch(void* const* d_in, const int* in_sizes, int n_in,
                              void* d_out, int out_size, void* d_ws, size_t ws_size,
                              hipStream_t stream)
{
    const float* h      = (const float*)d_in[0];
    const void*  ei     = d_in[1];
    const float* cancer = (const float*)d_in[2];
    const float* causal = (const float*)d_in[3];
    const float* W1     = (const float*)d_in[4];
    const float* b1     = (const float*)d_in[5];
    const float* W2     = (const float*)d_in[6];
    const float* b2     = (const float*)d_in[7];
    float* outp = (float*)d_out;

    const int nNodes = in_sizes[0] / EMBED;
    const int E      = in_sizes[1] / 2;

    // workspace layout
    const size_t WPB_OFF   = 8192;                      // 80 KB -> ends 90112
    const size_t PAIRS_OFF = 98304;
    const size_t pairsB    = ((size_t)E * 4 + 255) & ~(size_t)255;
    const size_t tabB      = (size_t)nNodes * ROWB;     // 9.6 MB each
    const size_t U_OFF     = PAIRS_OFF + pairsB;
    const size_t V_OFF     = (U_OFF + tabB + 255) & ~(size_t)255;
    const size_t need      = V_OFF + tabB;

    char* ws = (char*)d_ws;
    float* b1p  = (float*)(ws + 1024);
    float* wci  = (float*)(ws + 2048);
    float* wcj  = (float*)(ws + 3072);
    float* w2p  = (float*)(ws + 4096);
    short* Wpb  = (short*)(ws + WPB_OFF);

    if (ws_size >= need && nNodes <= 65536) {
        uint32_t* pairs = (uint32_t*)(ws + PAIRS_OFF);
        uint8_t*  u     = (uint8_t*)(ws + U_OFF);
        uint8_t*  v     = (uint8_t*)(ws + V_OFF);

        const int P = (E + 255) / 256;
        prep_fused<<<P + 161, 256, 0, stream>>>(cancer, W1, b1, W2, ei, E, P,
                                                b1p, wci, wcj, w2p, Wpb, pairs);
        proj_mfma<<<(nNodes + 63) / 64, 256, 0, stream>>>(h, Wpb, causal, b1p,
                                                          wci, wcj, u, v, nNodes);
        const int waves  = (E + 15) / 16;
        const int blocks = (waves + 3) / 4;
        edge_int8<<<blocks, 256, 0, stream>>>(pairs, u, v, w2p, b2, outp, E);
    } else {
        fallback_kernel<<<2048, 256, 0, stream>>>(ei, h, cancer, causal, W1, b1, W2, b2,
                                                  outp, E);
    }
}